// Round 1
// 294.583 us; speedup vs baseline: 1.0245x; 1.0245x over previous
//
#include <hip/hip_runtime.h>
#include <cstdint>
#include <cstddef>

// ---- problem constants ----
#define B_    4
#define S_    2048
#define D_    1024
#define H_    16
#define HD_   64
#define M_    8192      // B_*S_
#define NQKV  3072

typedef __bf16 bf16;
typedef __bf16 bf16x4 __attribute__((ext_vector_type(4)));
typedef __bf16 bf16x8 __attribute__((ext_vector_type(8)));
typedef float  f32x2  __attribute__((ext_vector_type(2)));
typedef float  f32x4  __attribute__((ext_vector_type(4)));
typedef float  f32x16 __attribute__((ext_vector_type(16)));
typedef unsigned short u16x4 __attribute__((ext_vector_type(4)));
typedef uint32_t u32x2 __attribute__((ext_vector_type(2)));
typedef uint32_t u32x4 __attribute__((ext_vector_type(4)));

// async global->LDS, 16B per lane. LDS dest is wave-uniform base + lane*16.
__device__ __forceinline__ void gl2lds16(const void* g, void* l) {
  __builtin_amdgcn_global_load_lds(
      (__attribute__((address_space(1))) void*)(uintptr_t)g,
      (__attribute__((address_space(3))) void*)l, 16, 0, 0);
}

__device__ __forceinline__ uint32_t pkbf16(float a, float b) {
  union { bf16 h[2]; uint32_t u; } z;
  z.h[0] = (bf16)a; z.h[1] = (bf16)b;
  return z.u;
}

// ---- prep: fp32 -> bf16 cast (x) ----
__global__ __launch_bounds__(256) void cast_f32_bf16(const float* __restrict__ in,
                                                     bf16* __restrict__ out, int n4) {
  int i = blockIdx.x * 256 + threadIdx.x;
  if (i >= n4) return;
  float4 v = ((const float4*)in)[i];
  bf16x4 o;
  o[0] = (bf16)v.x; o[1] = (bf16)v.y; o[2] = (bf16)v.z; o[3] = (bf16)v.w;
  ((bf16x4*)out)[i] = o;
}

// ---- prep: transpose + cast: in [R,C] fp32 -> out [C,R] bf16 ----
__global__ __launch_bounds__(256) void transpose_cast(const float* __restrict__ in,
                                                      bf16* __restrict__ out, int R, int C) {
  __shared__ float tile[32][33];
  int bx = blockIdx.x * 32, by = blockIdx.y * 32;
  int tx = threadIdx.x, ty = threadIdx.y;
#pragma unroll
  for (int i = 0; i < 32; i += 8)
    tile[ty + i][tx] = in[(size_t)(by + ty + i) * C + bx + tx];
  __syncthreads();
#pragma unroll
  for (int i = 0; i < 32; i += 8)
    out[(size_t)(bx + ty + i) * R + by + tx] = (bf16)tile[tx][ty + i];
}

// ---- 128x128 GEMM w/ XCD super-tiling: C[M,N] = A[M,K]*Bt[N,K]^T + bias ----
// bid&7 = XCD -> m-band of 8 tiles (A-band 2 MB, L2-resident); mi-inner, n-outer.
template <bool OUT_BF16>
__global__ __launch_bounds__(256) void gemm_bt(const bf16* __restrict__ A,
                                               const bf16* __restrict__ Bt,
                                               const float* __restrict__ bias,
                                               void* __restrict__ Cptr,
                                               int M, int N, int K) {
  __shared__ __align__(16) bf16 As[128 * 64];
  __shared__ __align__(16) bf16 Bs[128 * 64];
  const int tid  = threadIdx.x;
  const int lane = tid & 63, w = tid >> 6;
  const int lo   = lane & 15, quad = lane >> 4;
  const int xcd = blockIdx.x & 7, g = blockIdx.x >> 3;
  const int mi  = g & 7,          n = g >> 3;
  const int bm  = (xcd * 8 + mi) * 128, bn = n * 128;
  const int wm = (w >> 1) * 64,    wn = (w & 1) * 64;

  f32x4 acc[4][4];
  const f32x4 zero = {0.f, 0.f, 0.f, 0.f};
#pragma unroll
  for (int i = 0; i < 4; ++i)
#pragma unroll
    for (int j = 0; j < 4; ++j) acc[i][j] = zero;

  for (int k0 = 0; k0 < K; k0 += 64) {
#pragma unroll
    for (int c = 0; c < 4; ++c) {
      int seg = c * 4 + w;
      int idx = seg * 512 + lane * 8;
      int row = idx >> 6, col = idx & 63;
      gl2lds16(A  + (size_t)(bm + row) * K + k0 + col, As + seg * 512);
      gl2lds16(Bt + (size_t)(bn + row) * K + k0 + col, Bs + seg * 512);
    }
    __syncthreads();
#pragma unroll
    for (int ks = 0; ks < 2; ++ks) {
      bf16x8 av[4], bv[4];
#pragma unroll
      for (int i = 0; i < 4; ++i)
        av[i] = *(const bf16x8*)&As[(wm + i * 16 + lo) * 64 + ks * 32 + quad * 8];
#pragma unroll
      for (int j = 0; j < 4; ++j)
        bv[j] = *(const bf16x8*)&Bs[(wn + j * 16 + lo) * 64 + ks * 32 + quad * 8];
#pragma unroll
      for (int i = 0; i < 4; ++i)
#pragma unroll
        for (int j = 0; j < 4; ++j)
          acc[i][j] = __builtin_amdgcn_mfma_f32_16x16x32_bf16(av[i], bv[j], acc[i][j], 0, 0, 0);
    }
    __syncthreads();
  }
#pragma unroll
  for (int j = 0; j < 4; ++j) {
    int cg = bn + wn + j * 16 + lo;
    float bsv = bias[cg];
#pragma unroll
    for (int i = 0; i < 4; ++i) {
      int rg = bm + wm + i * 16 + quad * 4;
#pragma unroll
      for (int r = 0; r < 4; ++r) {
        float v = acc[i][j][r] + bsv;
        if (OUT_BF16) ((bf16*)Cptr)[(size_t)(rg + r) * N + cg] = (bf16)v;
        else          ((float*)Cptr)[(size_t)(rg + r) * N + cg] = v;
      }
    }
  }
}

// ---- 128x256 GEMM (qkv): doubles MFMA per barrier to amortize the per-iter
// vmcnt(0)+barrier drain at K=1024 (16 iters). Waves 2x2: each 64m x 128n,
// 4x8 16x16x32 MFMAs, 128 AGPR acc -> launch_bounds(256,2).
__global__ __launch_bounds__(256, 2) void gemm_bt_wide(const bf16* __restrict__ A,
                                                       const bf16* __restrict__ Bt,
                                                       const float* __restrict__ bias,
                                                       bf16* __restrict__ Cptr,
                                                       int M, int N, int K) {
  __shared__ __align__(16) bf16 As[128 * 64];   // 16 KB
  __shared__ __align__(16) bf16 Bs[256 * 64];   // 32 KB
  const int tid  = threadIdx.x;
  const int lane = tid & 63, w = tid >> 6;
  const int lo   = lane & 15, quad = lane >> 4;
  const int xcd = blockIdx.x & 7, g = blockIdx.x >> 3;
  const int mi  = g & 7,          n = g >> 3;
  const int bm  = (xcd * 8 + mi) * 128, bn = n * 256;
  const int wm = (w >> 1) * 64,    wn = (w & 1) * 128;

  f32x4 acc[4][8];
  const f32x4 zero = {0.f, 0.f, 0.f, 0.f};
#pragma unroll
  for (int i = 0; i < 4; ++i)
#pragma unroll
    for (int j = 0; j < 8; ++j) acc[i][j] = zero;

  for (int k0 = 0; k0 < K; k0 += 64) {
#pragma unroll
    for (int c = 0; c < 4; ++c) {
      int seg = c * 4 + w;
      int idx = seg * 512 + lane * 8;
      int row = idx >> 6, col = idx & 63;
      gl2lds16(A + (size_t)(bm + row) * K + k0 + col, As + seg * 512);
    }
#pragma unroll
    for (int c = 0; c < 8; ++c) {
      int seg = c * 4 + w;
      int idx = seg * 512 + lane * 8;
      int row = idx >> 6, col = idx & 63;
      gl2lds16(Bt + (size_t)(bn + row) * K + k0 + col, Bs + seg * 512);
    }
    __syncthreads();
#pragma unroll
    for (int ks = 0; ks < 2; ++ks) {
      bf16x8 av[4], bv[8];
#pragma unroll
      for (int i = 0; i < 4; ++i)
        av[i] = *(const bf16x8*)&As[(wm + i * 16 + lo) * 64 + ks * 32 + quad * 8];
#pragma unroll
      for (int j = 0; j < 8; ++j)
        bv[j] = *(const bf16x8*)&Bs[(wn + j * 16 + lo) * 64 + ks * 32 + quad * 8];
#pragma unroll
      for (int i = 0; i < 4; ++i)
#pragma unroll
        for (int j = 0; j < 8; ++j)
          acc[i][j] = __builtin_amdgcn_mfma_f32_16x16x32_bf16(av[i], bv[j], acc[i][j], 0, 0, 0);
    }
    __syncthreads();
  }
#pragma unroll
  for (int j = 0; j < 8; ++j) {
    int cg = bn + wn + j * 16 + lo;
    float bsv = bias[cg];
#pragma unroll
    for (int i = 0; i < 4; ++i) {
      int rg = bm + wm + i * 16 + quad * 4;
#pragma unroll
      for (int r = 0; r < 4; ++r)
        Cptr[(size_t)(rg + r) * N + cg] = (bf16)(acc[i][j][r] + bsv);
    }
  }
}

// ---- flash attention v9 ----
// v8 + VALU-cut package (counters said VALU-bound: MfmaUtil 25 / VALUBusy 54):
//  (1) P-relayout via v_permlane32_swap_b32: swap(Q8[bq],Q8[bq+2]) yields
//      {pd0,pd2} directly (own-half lo-lanes, partner-half hi-lanes) — replaces
//      8 ds_swizzle (__shfl_xor 32) + ~24 v_cndmask per tile, and takes the
//      LDS pipe off the exp2->PV critical path.
//  (2) packed f32 math: s*c2-16 and the p-sum as <2 x float> ops ->
//      v_pk_fma_f32 / v_pk_add_f32; lsum reduced once after the loop.
//  (3) V-stage 16-bit pack via v_perm_b32 (selectors 0x05040100 / 0x07060302)
//      instead of and/shr/insert — identical bytes, same swizzled b64 stores.
__global__ __launch_bounds__(256, 4) void flash_attn(const bf16* __restrict__ qkv,
                                                     bf16* __restrict__ out) {
  __shared__ __align__(16) bf16 Ks[2][64 * 64];    // 16 KB, chunk-swizzled rows
  __shared__ __align__(16) bf16 Vs[2][64 * 64];    // 16 KB, [d][s] chunk-swizzled

  const int tid  = threadIdx.x;
  const int lane = tid & 63, wq = tid >> 6;
  const int l31  = lane & 31;
  const int e    = lane >> 5;           // hi1
  const int hi8  = e * 8, hi4 = e * 4;

  const int bid = blockIdx.x;
  const int qb  = bid >> 6;             // 0..15
  const int bh  = bid & 63;
  const int h   = bh & 15;
  const int b   = bh >> 4;
  const int q0  = qb * 128;
  const size_t rowb = (size_t)b * S_;
  const bf16* qbase = qkv + rowb * NQKV + h * HD_;
  const bf16* kbase = qbase + D_;
  const bf16* vbase = qbase + 2 * D_;

  // ---- Q fragments straight from global (loop-invariant) ----
  bf16x8 qf[4];
  {
    const bf16* qrow = qbase + (size_t)(q0 + wq * 32 + l31) * NQKV;
#pragma unroll
    for (int c = 0; c < 4; ++c)
      qf[c] = *(const bf16x8*)(qrow + c * 16 + hi8);
  }

  // ---- K DMA indices: chunk ci = it*256+tid -> global (s, x), LDS contiguous ----
  int kq_off[2];
#pragma unroll
  for (int it = 0; it < 2; ++it) {
    int ci = it * 256 + tid;
    int s  = ci >> 3;
    int x  = (ci & 7) ^ (s & 7);
    kq_off[it] = s * NQKV + x * 8;
  }
  // ---- V staging indices ----
  int vs_d[2], vs_s[2], vs_off[2];
#pragma unroll
  for (int u = 0; u < 2; ++u) {
    int idx = u * 256 + tid;
    int d0 = (idx & 31) * 2;
    int s0 = (idx >> 5) * 4;
    vs_d[u] = d0;
    vs_s[u] = s0;
    // LDS elem offset of the lane's 4-s run in row d0 (chunk-XOR swizzle)
    vs_off[u] = (((s0 >> 3) ^ ((d0 >> 1) & 7)) * 8) + (s0 & 7);
  }

  uint32_t vreg[2][4];

  // ---- prologue: DMA K tile 0 into buf0; prefetch V tile 0 regs ----
#pragma unroll
  for (int it = 0; it < 2; ++it)
    gl2lds16(kbase + kq_off[it], &Ks[0][(it * 256 + wq * 64) * 8]);
#pragma unroll
  for (int u = 0; u < 2; ++u)
#pragma unroll
    for (int j = 0; j < 4; ++j)
      vreg[u][j] = *(const uint32_t*)(vbase + (size_t)(vs_s[u] + j) * NQKV + vs_d[u]);

  const f32x16 zero16 = {0.f,0.f,0.f,0.f,0.f,0.f,0.f,0.f,0.f,0.f,0.f,0.f,0.f,0.f,0.f,0.f};
  f32x16 oacc[2];
  oacc[0] = zero16; oacc[1] = zero16;
  f32x2 psv = {0.f, 0.f};               // per-lane packed p-sum, reduced after loop
  const float c2 = 0.125f * 1.44269504088896341f;   // scale * log2(e)

  for (int kt = 0; kt < 32; ++kt) {
    const int buf = kt & 1;
    // ---- write staged V regs to LDS (swizzled transpose, v_perm pack) ----
#pragma unroll
    for (int u = 0; u < 2; ++u) {
      int d0 = vs_d[u];
      uint32_t lo0 = __builtin_amdgcn_perm(vreg[u][1], vreg[u][0], 0x05040100u);
      uint32_t lo1 = __builtin_amdgcn_perm(vreg[u][3], vreg[u][2], 0x05040100u);
      uint32_t hi0 = __builtin_amdgcn_perm(vreg[u][1], vreg[u][0], 0x07060302u);
      uint32_t hi1 = __builtin_amdgcn_perm(vreg[u][3], vreg[u][2], 0x07060302u);
      u32x2 lov = {lo0, lo1}, hiv = {hi0, hi1};
      *(u32x2*)&Vs[buf][(d0 + 0) * 64 + vs_off[u]] = lov;
      *(u32x2*)&Vs[buf][(d0 + 1) * 64 + vs_off[u]] = hiv;
    }
    __syncthreads();

    // ---- async K DMA for NEXT tile into buf^1 (drained by next barrier) ----
    {
      int ktn = (kt + 1 < 32) ? kt + 1 : 31;
      const bf16* kb = kbase + (size_t)ktn * 64 * NQKV;
#pragma unroll
      for (int it = 0; it < 2; ++it)
        gl2lds16(kb + kq_off[it], &Ks[buf ^ 1][(it * 256 + wq * 64) * 8]);
    }
    // ---- V register prefetch for next tile ----
    {
      int ktn = (kt + 1 < 32) ? kt + 1 : 31;
      const bf16* vb = vbase + (size_t)ktn * 64 * NQKV;
#pragma unroll
      for (int u = 0; u < 2; ++u)
#pragma unroll
        for (int j = 0; j < 4; ++j)
          vreg[u][j] = *(const uint32_t*)(vb + (size_t)(vs_s[u] + j) * NQKV + vs_d[u]);
    }

    // ---- S^T = K.Q^T : 2 independent chains [32k x 32q], XOR-swizzled reads ----
    f32x16 sacc[2];
#pragma unroll
    for (int kk = 0; kk < 2; ++kk) {
      sacc[kk] = zero16;
      int srow = kk * 32 + l31;
      int swz  = (srow & 7) * 8;
#pragma unroll
      for (int c = 0; c < 4; ++c) {
        bf16x8 kf = *(const bf16x8*)&Ks[buf][srow * 64 + ((c * 16 + hi8) ^ swz)];
        sacc[kk] = __builtin_amdgcn_mfma_f32_32x32x16_bf16(kf, qf[c], sacc[kk], 0, 0, 0);
      }
    }

    // ---- per 32k-half: exp2 -> pack -> permlane relayout -> O-MFMAs ----
#pragma unroll
    for (int kk = 0; kk < 2; ++kk) {
      uint32_t Q8[8];
#pragma unroll
      for (int i = 0; i < 8; ++i) {
        f32x2 sv;
        sv[0] = sacc[kk][2 * i];
        sv[1] = sacc[kk][2 * i + 1];
        f32x2 t = sv * c2 - 16.0f;                 // v_pk_fma_f32
        float p0 = __builtin_amdgcn_exp2f(t[0]);
        float p1 = __builtin_amdgcn_exp2f(t[1]);
        psv += (f32x2){p0, p1};                    // v_pk_add_f32
        Q8[i] = pkbf16(p0, p1);
      }
#pragma unroll
      for (int mh = 0; mh < 2; ++mh) {
        const int m = kk * 2 + mh, bq = mh * 4;
        u32x4 pd;
#if __has_builtin(__builtin_amdgcn_permlane32_swap)
        u32x2 w0 = __builtin_amdgcn_permlane32_swap(Q8[bq],     Q8[bq + 2], false, false);
        u32x2 w1 = __builtin_amdgcn_permlane32_swap(Q8[bq + 1], Q8[bq + 3], false, false);
        pd[0] = w0[0]; pd[1] = w1[0]; pd[2] = w0[1]; pd[3] = w1[1];
#else
        uint32_t s0 = e ? Q8[bq]     : Q8[bq + 2];
        uint32_t s1 = e ? Q8[bq + 1] : Q8[bq + 3];
        uint32_t r0 = __shfl_xor(s0, 32);
        uint32_t r1 = __shfl_xor(s1, 32);
        pd[0] = e ? r0 : Q8[bq];
        pd[1] = e ? r1 : Q8[bq + 1];
        pd[2] = e ? Q8[bq + 2] : r0;
        pd[3] = e ? Q8[bq + 3] : r1;
#endif
        bf16x8 pf = __builtin_bit_cast(bf16x8, pd);
#pragma unroll
        for (int dt = 0; dt < 2; ++dt) {
          int drow = dt * 32 + l31;
          int swv  = (drow >> 1) & 7;
          bf16x8 vf = *(const bf16x8*)&Vs[buf][drow * 64 + (((m * 2 + e) ^ swv) * 8)];
          oacc[dt] = __builtin_amdgcn_mfma_f32_32x32x16_bf16(vf, pf, oacc[dt], 0, 0, 0);
        }
      }
    }
  }

  float lsum = psv[0] + psv[1];
  lsum += __shfl_xor(lsum, 32);

  // ---- epilogue: O^T/lsum -> LDS (chunk-swizzled, reuse Vs) -> 16B stores ----
  __syncthreads();                       // all Ks/Vs reads done; safe to reuse
  bf16* Os = (bf16*)Vs;                  // [128][64] bf16, chunk-XOR ((row>>1)&7)
  {
    float inv = 1.f / lsum;
    int ql = wq * 32 + l31;
    int swO = (ql >> 1) & 7;
#pragma unroll
    for (int dt = 0; dt < 2; ++dt) {
#pragma unroll
      for (int g = 0; g < 4; ++g) {
        bf16x4 ov;
#pragma unroll
        for (int jj = 0; jj < 4; ++jj) ov[jj] = (bf16)(oacc[dt][g * 4 + jj] * inv);
        *(bf16x4*)&Os[ql * 64 + (((dt * 4 + g) ^ swO) * 8) + hi4] = ov;
      }
    }
  }
  __syncthreads();
#pragma unroll
  for (int it = 0; it < 4; ++it) {
    int idx = it * 256 + tid;
    int row = idx >> 3, c8 = idx & 7;
    bf16x8 t = *(const bf16x8*)&Os[row * 64 + ((c8 ^ ((row >> 1) & 7)) * 8)];
    *(bf16x8*)&out[(rowb + q0 + row) * D_ + h * HD_ + c8 * 8] = t;
  }
}

extern "C" void kernel_launch(void* const* d_in, const int* in_sizes, int n_in,
                              void* d_out, int out_size, void* d_ws, size_t ws_size,
                              hipStream_t stream) {
  const float* x     = (const float*)d_in[0];
  const float* w_qkv = (const float*)d_in[1];
  const float* b_qkv = (const float*)d_in[2];
  const float* w_out = (const float*)d_in[3];
  const float* b_out = (const float*)d_in[4];
  float* out = (float*)d_out;

  char* ws = (char*)d_ws;
  bf16* xb    = (bf16*)(ws);                         // 16 MB
  bf16* wqkvT = (bf16*)(ws + (size_t)16777216);      //  6 MB
  bf16* woutT = (bf16*)(ws + (size_t)23068672);      //  2 MB
  bf16* qkvb  = (bf16*)(ws + (size_t)25165824);      // 48 MB
  bf16* attnb = (bf16*)(ws + (size_t)75497472);      // 16 MB

  cast_f32_bf16<<<(M_ * D_ / 4 + 255) / 256, 256, 0, stream>>>(x, xb, M_ * D_ / 4);
  transpose_cast<<<dim3(NQKV / 32, D_ / 32), dim3(32, 8), 0, stream>>>(w_qkv, wqkvT, D_, NQKV);
  transpose_cast<<<dim3(D_ / 32, D_ / 32), dim3(32, 8), 0, stream>>>(w_out, woutT, D_, D_);

  gemm_bt_wide<<<(M_ / 128) * (NQKV / 256), 256, 0, stream>>>(
      xb, wqkvT, b_qkv, qkvb, M_, NQKV, D_);

  flash_attn<<<B_ * H_ * (S_ / 128), 256, 0, stream>>>(qkvb, attnb);

  gemm_bt<false><<<(M_ / 128) * (D_ / 128), 256, 0, stream>>>(
      attnb, woutT, b_out, (void*)out, M_, D_, D_);
}